// Round 6
// baseline (102.808 us; speedup 1.0000x reference)
//
#include <hip/hip_runtime.h>

#define S 2000
#define P 2500
#define R 5
#define HALF (S / 2)      // 1000 float4 elements per row
#define NIT 16            // ceil(HALF/64) wave iterations

typedef float floatx4 __attribute__((ext_vector_type(4)));

// One wave per (h,p): handles all R=5 rows. Element-invariants (load, tol,
// fsum, sgn) computed once, reused 5x. No LDS, no barriers, plain stores.
__global__ __launch_bounds__(256) void grad_kernel(
    const float* __restrict__ filtration,   // (S,2) interleaved
    const float* __restrict__ bars0,        // (P,R)
    const float* __restrict__ bars1,        // (P,R)
    const float* __restrict__ sample_pts,   // (P,2)
    float* __restrict__ out,                // (2,P,R)
    float* __restrict__ gm0, float* __restrict__ gc0,
    float* __restrict__ gm1, float* __restrict__ gc1)
{
    int job = __builtin_amdgcn_readfirstlane(blockIdx.x * 4 + (threadIdx.x >> 6)); // h*P + p
    int lane = threadIdx.x & 63;
    int h = job / P;
    int p = job - h * P;

    const float* bars = h ? bars1 : bars0;
    float* gm = h ? gm1 : gm0;
    float* gc = h ? gc1 : gc0;

    float ptx = sample_pts[2 * p];
    float pty = sample_pts[2 * p + 1];
    float psum = ptx + pty;

    // Per-r line tables (wave-uniform). Rounding matches reference:
    // ks = (k-2)*scale exact (k-2 in {-2..2}); line = ks + pt, one rounding.
    float barv[R], lx[R][5], ly[R][5];
#pragma unroll
    for (int r = 0; r < R; ++r) {
        float bar = bars[p * R + r];
        barv[r] = bar;
        float sc = bar + 0.01f;               // GRID_RES
#pragma unroll
        for (int k = 0; k < 5; ++k) {
            float ks = (float)(k - 2) * sc;
            lx[r][k] = ks + ptx;
            ly[r][k] = ks + pty;
        }
    }

    // fused out-copy: out[h,p,r] = bar
    if (lane == 0) {
#pragma unroll
        for (int r = 0; r < R; ++r)
            out[(size_t)h * (P * R) + p * R + r] = barv[r];
    }

    const floatx4* filt4 = (const floatx4*)filtration;

    float* gmr[R];
#pragma unroll
    for (int r = 0; r < R; ++r)
        gmr[r] = gm + ((size_t)r * P + p) * (size_t)(2 * S);

    float axmax[R], axmin[R], aymax[R], aymin[R];
#pragma unroll
    for (int r = 0; r < R; ++r) {
        axmax[r] = 0.f; axmin[r] = 0.f; aymax[r] = 0.f; aymin[r] = 0.f;
    }

#pragma unroll
    for (int it = 0; it < NIT; ++it) {
        int j = lane + 64 * it;
        if (it < NIT - 1 || j < HALF) {       // compile-time for it<15
            floatx4 f = filt4[j];
            // r-invariant per-element work (once per 5 rows):
            float tolx0 = __fadd_rn(0.01f, __fmul_rn(1e-5f, __builtin_fabsf(f.x)));
            float toly0 = __fadd_rn(0.01f, __fmul_rn(1e-5f, __builtin_fabsf(f.y)));
            float tolx1 = __fadd_rn(0.01f, __fmul_rn(1e-5f, __builtin_fabsf(f.z)));
            float toly1 = __fadd_rn(0.01f, __fmul_rn(1e-5f, __builtin_fabsf(f.w)));
            float s0 = f.x + f.y;
            float s1 = f.z + f.w;
            float sgn0 = (s0 > psum) ? 1.0f : ((s0 < psum) ? -1.0f : 0.0f);
            float sgn1 = (s1 > psum) ? 1.0f : ((s1 < psum) ? -1.0f : 0.0f);

#pragma unroll
            for (int r = 0; r < R; ++r) {
                float lastx = lx[r][4], lasty = ly[r][4];
                floatx4 o;
                {   // close_x, pair 0 (min-of-|d| == any(|d|<=tol), exact)
                    float m = fminf(fminf(__builtin_fabsf(lx[r][0] - f.x),
                                          __builtin_fabsf(lx[r][1] - f.x)),
                                    fminf(__builtin_fabsf(lx[r][2] - f.x),
                                          __builtin_fabsf(lx[r][3] - f.x)));
                    m = fminf(m, __builtin_fabsf(lastx - f.x));
                    float t = (m <= tolx0) ? sgn0 : 0.0f;
                    o.x = (f.y <= lasty) ? t : 0.0f;
                }
                {   // close_y, pair 0
                    float m = fminf(fminf(__builtin_fabsf(ly[r][0] - f.y),
                                          __builtin_fabsf(ly[r][1] - f.y)),
                                    fminf(__builtin_fabsf(ly[r][2] - f.y),
                                          __builtin_fabsf(ly[r][3] - f.y)));
                    m = fminf(m, __builtin_fabsf(lasty - f.y));
                    float t = (m <= toly0) ? sgn0 : 0.0f;
                    o.y = (f.x <= lastx) ? t : 0.0f;
                }
                {   // close_x, pair 1
                    float m = fminf(fminf(__builtin_fabsf(lx[r][0] - f.z),
                                          __builtin_fabsf(lx[r][1] - f.z)),
                                    fminf(__builtin_fabsf(lx[r][2] - f.z),
                                          __builtin_fabsf(lx[r][3] - f.z)));
                    m = fminf(m, __builtin_fabsf(lastx - f.z));
                    float t = (m <= tolx1) ? sgn1 : 0.0f;
                    o.z = (f.w <= lasty) ? t : 0.0f;
                }
                {   // close_y, pair 1
                    float m = fminf(fminf(__builtin_fabsf(ly[r][0] - f.w),
                                          __builtin_fabsf(ly[r][1] - f.w)),
                                    fminf(__builtin_fabsf(ly[r][2] - f.w),
                                          __builtin_fabsf(ly[r][3] - f.w)));
                    m = fminf(m, __builtin_fabsf(lasty - f.w));
                    float t = (m <= toly1) ? sgn1 : 0.0f;
                    o.w = (f.z <= lastx) ? t : 0.0f;
                }
                axmax[r] = fmaxf(axmax[r], fmaxf(o.x, o.z));
                axmin[r] = fminf(axmin[r], fminf(o.x, o.z));
                aymax[r] = fmaxf(aymax[r], fmaxf(o.y, o.w));
                aymin[r] = fminf(aymin[r], fminf(o.y, o.w));
                *(floatx4*)(gmr[r] + (size_t)j * 4) = o;
            }
        }
    }

#pragma unroll
    for (int r = 0; r < R; ++r) {
        bool anyUx = __any(axmax[r] > 0.f);
        bool anyLx = __any(axmin[r] < 0.f);
        bool anyUy = __any(aymax[r] > 0.f);
        bool anyLy = __any(aymin[r] < 0.f);
        if (lane == 0) {
            float cxv = anyUx ? -1.0f : (anyLx ? 1.0f : 0.0f);
            float cyv = anyUy ? -1.0f : (anyLy ? 1.0f : 0.0f);
            *(float2*)(gc + ((size_t)r * P + p) * 2) = make_float2(cxv, cyv);
        }
    }
}

extern "C" void kernel_launch(void* const* d_in, const int* in_sizes, int n_in,
                              void* d_out, int out_size, void* d_ws, size_t ws_size,
                              hipStream_t stream) {
    const float* filtration = (const float*)d_in[0];   // (2000,2)
    const float* bars_h0    = (const float*)d_in[1];   // (2500,5)
    const float* bars_h1    = (const float*)d_in[2];   // (2500,5)
    const float* sample_pts = (const float*)d_in[3];   // (2500,2)

    float* out = (float*)d_out;
    float* o_stack = out;                                 // 2*P*R
    float* gm0     = o_stack + (size_t)2 * P * R;         // R*P*2S
    float* gc0     = gm0 + (size_t)R * P * 2 * S;         // R*P*2
    float* gm1     = gc0 + (size_t)R * P * 2;             // R*P*2S
    float* gc1     = gm1 + (size_t)R * P * 2 * S;         // R*P*2

    grad_kernel<<<(2 * P) / 4, 256, 0, stream>>>(filtration, bars_h0, bars_h1, sample_pts,
                                                 o_stack, gm0, gc0, gm1, gc1);
}

// Round 7
// 86.028 us; speedup vs baseline: 1.1951x; 1.1951x over previous
//
#include <hip/hip_runtime.h>

#define S 2000
#define P 2500
#define R 5
#define HALF (S / 2)      // 1000 float4 elements per row

typedef float floatx4 __attribute__((ext_vector_type(4)));

// 4 waves/WG, one (h,r,p) row per wave. Inner loop: load 4 float4 -> compute
// 4 output vectors -> burst 4 contiguous 1KB stores (store-depth for HBM).
// gc flags via lane-mask bools (SALU), reduced with __any at the end.
__global__ __launch_bounds__(256) void grad_kernel(
    const float* __restrict__ filtration,   // (S,2) interleaved
    const float* __restrict__ bars0,        // (P,R)
    const float* __restrict__ bars1,        // (P,R)
    const float* __restrict__ sample_pts,   // (P,2)
    float* __restrict__ out,                // (2,P,R)
    float* __restrict__ gm0, float* __restrict__ gc0,
    float* __restrict__ gm1, float* __restrict__ gc1)
{
    int job = blockIdx.x * 4 + (threadIdx.x >> 6);   // h*(R*P) + r*P + p
    int lane = threadIdx.x & 63;
    int h = job / (R * P);
    int rem = job - h * (R * P);
    int r = rem / P;
    int p = rem - r * P;

    const float* bars = h ? bars1 : bars0;
    float* gm = h ? gm1 : gm0;
    float* gc = h ? gc1 : gc0;

    float bar = bars[p * R + r];
    float scale = bar + 0.01f;               // GRID_RES
    float ptx = sample_pts[2 * p];
    float pty = sample_pts[2 * p + 1];
    float psum = ptx + pty;

    float lxk[5], lyk[5];
#pragma unroll
    for (int k = 0; k < 5; ++k) {
        float ks = (float)(k - 2) * scale;   // exact mul, k-2 in {-2..2}
        lxk[k] = ks + ptx;                   // single rounding (matches np)
        lyk[k] = ks + pty;
    }
    float lastx = lxk[4];
    float lasty = lyk[4];

    if (lane == 0) out[(size_t)h * (P * R) + p * R + r] = bar;

    const floatx4* filt4 = (const floatx4*)filtration;
    float* gmrow = gm + ((size_t)r * P + p) * (size_t)(2 * S);

    bool aUx = false, aLx = false, aUy = false, aLy = false;

#pragma unroll
    for (int g = 0; g < 4; ++g) {
        floatx4 f[4], o[4];
        // ---- load phase (L1-resident after first touch) ----
#pragma unroll
        for (int u = 0; u < 4; ++u) {
            int j = lane + 256 * g + 64 * u;
            if ((g < 3 || u < 3) || j < HALF)      // mask only g=3,u=3
                f[u] = filt4[j];
        }
        // ---- compute phase ----
#pragma unroll
        for (int u = 0; u < 4; ++u) {
            int j = lane + 256 * g + 64 * u;
            if ((g < 3 || u < 3) || j < HALF) {
                floatx4 fv = f[u], ov;
                {   // pair 0 (s = 2j)
                    float fx = fv.x, fy = fv.y;
                    float tolx = __fadd_rn(0.01f, __fmul_rn(1e-5f, __builtin_fabsf(fx)));
                    float toly = __fadd_rn(0.01f, __fmul_rn(1e-5f, __builtin_fabsf(fy)));
                    // min(|d_k|) <= tol  <=>  any(|d_k| <= tol)   (exact)
                    float mx = fminf(fminf(fminf(__builtin_fabsf(lxk[0] - fx),
                                                 __builtin_fabsf(lxk[1] - fx)),
                                           fminf(__builtin_fabsf(lxk[2] - fx),
                                                 __builtin_fabsf(lxk[3] - fx))),
                                     __builtin_fabsf(lxk[4] - fx));
                    float my = fminf(fminf(fminf(__builtin_fabsf(lyk[0] - fy),
                                                 __builtin_fabsf(lyk[1] - fy)),
                                           fminf(__builtin_fabsf(lyk[2] - fy),
                                                 __builtin_fabsf(lyk[3] - fy))),
                                     __builtin_fabsf(lyk[4] - fy));
                    bool cx = (mx <= tolx) && (fy <= lasty);
                    bool cy = (my <= toly) && (fx <= lastx);
                    float fsum = fx + fy;
                    bool ab = fsum > psum, be = fsum < psum;
                    float sgn = ab ? 1.0f : (be ? -1.0f : 0.0f);
                    ov.x = cx ? sgn : 0.0f;
                    ov.y = cy ? sgn : 0.0f;
                    aUx = aUx || (cx && ab);  aLx = aLx || (cx && be);
                    aUy = aUy || (cy && ab);  aLy = aLy || (cy && be);
                }
                {   // pair 1 (s = 2j+1)
                    float fx = fv.z, fy = fv.w;
                    float tolx = __fadd_rn(0.01f, __fmul_rn(1e-5f, __builtin_fabsf(fx)));
                    float toly = __fadd_rn(0.01f, __fmul_rn(1e-5f, __builtin_fabsf(fy)));
                    float mx = fminf(fminf(fminf(__builtin_fabsf(lxk[0] - fx),
                                                 __builtin_fabsf(lxk[1] - fx)),
                                           fminf(__builtin_fabsf(lxk[2] - fx),
                                                 __builtin_fabsf(lxk[3] - fx))),
                                     __builtin_fabsf(lxk[4] - fx));
                    float my = fminf(fminf(fminf(__builtin_fabsf(lyk[0] - fy),
                                                 __builtin_fabsf(lyk[1] - fy)),
                                           fminf(__builtin_fabsf(lyk[2] - fy),
                                                 __builtin_fabsf(lyk[3] - fy))),
                                     __builtin_fabsf(lyk[4] - fy));
                    bool cx = (mx <= tolx) && (fy <= lasty);
                    bool cy = (my <= toly) && (fx <= lastx);
                    float fsum = fx + fy;
                    bool ab = fsum > psum, be = fsum < psum;
                    float sgn = ab ? 1.0f : (be ? -1.0f : 0.0f);
                    ov.z = cx ? sgn : 0.0f;
                    ov.w = cy ? sgn : 0.0f;
                    aUx = aUx || (cx && ab);  aLx = aLx || (cx && be);
                    aUy = aUy || (cy && ab);  aLy = aLy || (cy && be);
                }
                o[u] = ov;
            }
        }
        // ---- burst store phase: 4 contiguous 1KB stores back-to-back ----
#pragma unroll
        for (int u = 0; u < 4; ++u) {
            int j = lane + 256 * g + 64 * u;
            if ((g < 3 || u < 3) || j < HALF)
                *(floatx4*)(gmrow + (size_t)j * 4) = o[u];
        }
    }

    bool anyUx = __any(aUx);
    bool anyLx = __any(aLx);
    bool anyUy = __any(aUy);
    bool anyLy = __any(aLy);
    if (lane == 0) {
        float cxv = anyUx ? -1.0f : (anyLx ? 1.0f : 0.0f);
        float cyv = anyUy ? -1.0f : (anyLy ? 1.0f : 0.0f);
        *(float2*)(gc + ((size_t)r * P + p) * 2) = make_float2(cxv, cyv);
    }
}

extern "C" void kernel_launch(void* const* d_in, const int* in_sizes, int n_in,
                              void* d_out, int out_size, void* d_ws, size_t ws_size,
                              hipStream_t stream) {
    const float* filtration = (const float*)d_in[0];   // (2000,2)
    const float* bars_h0    = (const float*)d_in[1];   // (2500,5)
    const float* bars_h1    = (const float*)d_in[2];   // (2500,5)
    const float* sample_pts = (const float*)d_in[3];   // (2500,2)

    float* out = (float*)d_out;
    float* o_stack = out;                                 // 2*P*R
    float* gm0     = o_stack + (size_t)2 * P * R;         // R*P*2S
    float* gc0     = gm0 + (size_t)R * P * 2 * S;         // R*P*2
    float* gm1     = gc0 + (size_t)R * P * 2;             // R*P*2S
    float* gc1     = gm1 + (size_t)R * P * 2 * S;         // R*P*2

    grad_kernel<<<(2 * R * P) / 4, 256, 0, stream>>>(filtration, bars_h0, bars_h1, sample_pts,
                                                     o_stack, gm0, gc0, gm1, gc1);
}